// Round 12
// baseline (467.966 us; speedup 1.0000x reference)
//
#include <hip/hip_runtime.h>
#include <hip/hip_bf16.h>

#define BB 512
#define SS 1024
#define NI 20
#define HH 64
#define NG 256   // 4*H
#define MB4 4    // batch-dirs per block (1 cell per lane)
#define PAD 80   // h-row stride in f16
#define TSTR 257 // x-table row stride (floats)

typedef unsigned short u16;
typedef unsigned int u32;
typedef unsigned long long u64;
typedef _Float16 f16;
typedef f16 f16x8 __attribute__((ext_vector_type(8)));
typedef float f32x4 __attribute__((ext_vector_type(4)));

#define LOG2E 1.4426950408889634f

__device__ __forceinline__ float bf2f(u16 b) { return __uint_as_float(((u32)b) << 16); }
// mode==1: data is bf16; mode==0: data is fp32
__device__ __forceinline__ float ldw(const void* p, int idx, int mode) {
  return mode ? bf2f(((const u16*)p)[idx]) : ((const float*)p)[idx];
}
__device__ __forceinline__ float frcp(float x) { return __builtin_amdgcn_rcpf(x); }
__device__ __forceinline__ float fexp2(float x) { return __builtin_amdgcn_exp2f(x); }

// ---- epilogue as a NOINLINE function: its register pressure must not leak into
// the K-loop's scheduling region (r11 lesson: fused epilogue cost +70 us in-loop
// via conservative load-hoisting under whole-function VGPR pressure).
__device__ __attribute__((noinline))
void epilogue_fn(int t, int dir, int b0, int mode, u64 lens_packed,
                 float* hs,          // [MB4][64] final h
                 short* tok_s,       // [pos][m], tok+1
                 float* fp,          // 512-float scratch
                 float* w1s,         // [64][65]
                 float* avg2,        // [80]
                 float* c1w2,        // [400]
                 float* c2r,         // [MB4][100]
                 const void* conv1_w, const void* conv2_w, const void* conv2_b,
                 const void* fc1_w, const void* fc1_b,
                 float* fc1acc) {
  int len_m[MB4];
#pragma unroll
  for (int m = 0; m < MB4; ++m) len_m[m] = (int)((lens_packed >> (16 * m)) & 0xFFFFull);

  // stage fc1_w dir-slice coalesced: w1s[o][u] = fc1_w[o*228 + dir*64 + u]
  for (int i = t; i < 64 * 64; i += 256) {
    int o = i >> 6, u = i & 63;
    w1s[o * 65 + u] = ldw(fc1_w, o * 228 + dir * 64 + u, mode);
  }
  __syncthreads();

  // fc1 partial from this dir's h: thread (o=t&63, g=t>>6)
  for (int m = 0; m < MB4; ++m) {
    int o = t & 63, g = t >> 6;
    float v = 0.f;
#pragma unroll
    for (int u = g * 16; u < g * 16 + 16; ++u)
      v = fmaf(w1s[o * 65 + u], hs[m * 64 + u], v);
    fp[g * 64 + o] = v;
    __syncthreads();
    if (t < 64)
      atomicAdd(&fc1acc[(size_t)(b0 + m) * 64 + t],
                fp[t] + fp[64 + t] + fp[128 + t] + fp[192 + t]);
    __syncthreads();
  }

  if (dir == 1) {
    // conv path (verified r1-r11 logic): contributes W1[:,128:228].relu(c2) + b1
    for (int i = t; i < 400; i += 256) c1w2[i] = ldw(conv1_w, i, mode);
    __syncthreads();
    for (int m = 0; m < MB4; ++m) {
      int bw = len_m[m] >> 2;
      if (t < 160) {
        int half = t / 80, u = t - half * 80;
        int k = u / 20, cc = u % 20;
        int start = k * bw, mid = start + (bw >> 1), end = start + bw;
        int s0 = half ? mid : start, s1 = half ? end : mid;
        float sum = 0.f;
        for (int s = s0; s < s1; ++s) {
          // faithful torch reshape: flat f = s*20+cc of the [20,1024] map
          int f = s * 20 + cc;
          int tk = (int)tok_s[(f & 1023) * MB4 + m] - 1;
          if (tk >= 0) sum += c1w2[(f >> 10) * 20 + tk];
        }
        fp[half * 80 + u] = sum;
      }
      __syncthreads();
      if (t < 80) avg2[t] = (fp[t] + fp[80 + t]) / (float)bw;
      __syncthreads();
      if (t < 100) {
        float dot = ldw(conv2_b, t, mode);
#pragma unroll
        for (int qq = 0; qq < 80; ++qq)
          dot += avg2[qq] * ldw(conv2_w, t * 80 + qq, mode);
        c2r[m * 100 + t] = dot > 0.f ? dot : 0.f;  // relu
      }
      __syncthreads();
    }
    for (int m = 0; m < MB4; ++m) {
      int o = t & 63, g = t >> 6;
      float v = 0.f;
#pragma unroll
      for (int j = g * 25; j < g * 25 + 25; ++j)
        v = fmaf(ldw(fc1_w, o * 228 + 128 + j, mode), c2r[m * 100 + j], v);
      fp[g * 64 + o] = v;
      __syncthreads();
      if (t < 64)
        atomicAdd(&fc1acc[(size_t)(b0 + m) * 64 + t],
                  fp[t] + fp[64 + t] + fp[128 + t] + fp[192 + t] + ldw(fc1_b, t, mode));
      __syncthreads();
    }
  }
}

// ---- BiLSTM + folded head contributions: 256 blocks x 256 thr, 1 wave/SIMD ----
// Block = (dir, 4 batches). Wave w owns units 16w..16w+15, 4 gate types in-lane;
// lane (l,q) = cell (batch q, unit 16w+l); A-rows dup h[l>>2] 4x. x-projection
// rides MFMA C-init from LDS table (prefetched 1 step ahead) -> 8 MFMA/step in
// ONE serial C-chain per gate type (r10: accumulator forwarding is free; split
// regressed). Weights prescaled: i,f,o by -log2e, g by +2log2e (exp2-ready).
// Epilogue (linear head fold into fc1acc) lives in a noinline function.
__global__ __launch_bounds__(256)
void lstm_kernel(const void* in1,
                 const void* Wih_f, const void* Whh_f, const void* b_f,
                 const void* Wih_b, const void* Whh_b, const void* b_b,
                 const void* conv1_w, const void* conv2_w, const void* conv2_b,
                 const void* fc1_w, const void* fc1_b,
                 float* fc1acc) {
  int bx = blockIdx.x;          // 0..255
  int dir = bx >> 7;
  int b0 = (bx & 127) * MB4;
  int t = threadIdx.x;
  int w = t >> 6, lane = t & 63, l = lane & 15, q = lane >> 4;
  int bsel = l >> 2;            // batch whose h this lane's A-row carries

  __shared__ __align__(16) float table[21 * TSTR];  // 21.6 KB; doubles as extract staging
  __shared__ __align__(16) f16 hbuf[2][MB4][PAD];
  __shared__ short tok_s[SS * MB4];                 // [pos][m], stores tok+1
  __shared__ u64 red[256];                          // reused as float scratch in epilogue
  __shared__ float w1s[64 * 65];                    // fc1_w dir-slice (padded)
  __shared__ float hs[MB4][64];                     // final h, f32
  __shared__ float c2r[MB4][100];                   // relu(c2) (bwd only)
  __shared__ float avg2[80];
  __shared__ float c1w2[400];
  __shared__ int mode_sh;

  // ---- mode probe: b_f read as bf16; fp32 shows wild exponents ----
  if (t == 0) mode_sh = 1;
  __syncthreads();
  {
    float v = bf2f(((const u16*)b_f)[t]);
    if (!(fabsf(v) < 1000.0f)) atomicAnd(&mode_sh, 0);
  }
  __syncthreads();
  int mode = mode_sh;
  const void* Wih = dir ? Wih_b : Wih_f;
  const void* Whh = dir ? Whh_b : Whh_f;
  const void* bv  = dir ? b_b   : b_f;

  // ---- token extraction for this block's 4 batches (staged through `table` memory) ----
  u64 cnt = 0;  // packed 4x16-bit valid counts
  for (int m = 0; m < MB4; ++m) {
    if (mode) {
      u32* st = (u32*)table;
      for (int k0 = 0; k0 < 4; ++k0) {
        const u32* src = (const u32*)in1 + ((size_t)(b0 + m) * SS + k0 * 256) * 10;
#pragma unroll
        for (int i = 0; i < 10; ++i) st[t + i * 256] = src[t + i * 256];  // coalesced
        __syncthreads();
        const u32* row = st + t * 10;
        int tok = -1;
#pragma unroll
        for (int ww = 0; ww < 10; ++ww) {
          u32 u = row[ww];
          if (u & 0xFFFFu) tok = 2 * ww;
          if (u >> 16)     tok = 2 * ww + 1;
        }
        tok_s[(k0 * 256 + t) * MB4 + m] = (short)(tok + 1);
        cnt += (u64)(tok >= 0) << (16 * m);
        __syncthreads();
      }
    } else {
      float4* st = (float4*)table;
      for (int k0 = 0; k0 < 4; ++k0) {
        const float4* src = (const float4*)((const float*)in1 + ((size_t)(b0 + m) * SS + k0 * 256) * 20);
#pragma unroll
        for (int i = 0; i < 5; ++i) st[t + i * 256] = src[t + i * 256];  // coalesced 16B/lane
        __syncthreads();
        const float* row = (const float*)table + t * 20;
        int tok = -1;
#pragma unroll
        for (int ww = 0; ww < 20; ++ww)
          if (row[ww] != 0.f) tok = ww;
        tok_s[(k0 * 256 + t) * MB4 + m] = (short)(tok + 1);
        cnt += (u64)(tok >= 0) << (16 * m);
        __syncthreads();
      }
    }
  }
  // lens: packed u64 tree reduction
  red[t] = cnt;
  __syncthreads();
  for (int stp = 128; stp > 0; stp >>= 1) {
    if (t < stp) red[t] += red[t + stp];
    __syncthreads();
  }
  u64 lens_packed = red[0];
  __syncthreads();

  // ---- x-projection table: table[tok+1][g] = scl_g * (W_ih[g][tok] + b[g]); row 0 = bias ----
  for (int idx = t; idx < 21 * 256; idx += 256) {
    int r = idx >> 8, g = idx & 255;
    float scl = ((g >> 6) == 2) ? (2.f * LOG2E) : (-LOG2E);
    float v = ldw(bv, g, mode);
    if (r > 0) v += ldw(Wih, g * NI + (r - 1), mode);
    table[r * TSTR + g] = scl * v;
  }
  // ---- W_hh B-fragments: n=lane&15 -> gate col (unit 16w+l, type tt), k=q*8+j ----
  f16x8 Bf[4][2];
#pragma unroll
  for (int tt = 0; tt < 4; ++tt) {
    float scl = (tt == 2) ? (2.f * LOG2E) : (-LOG2E);
    int g = 64 * tt + 16 * w + l;
#pragma unroll
    for (int kc = 0; kc < 2; ++kc) {
      f16x8 v;
#pragma unroll
      for (int j = 0; j < 8; ++j)
        v[j] = (f16)(scl * ldw(Whh, g * HH + kc * 32 + q * 8 + j, mode));
      Bf[tt][kc] = v;
    }
  }
  for (int idx = t; idx < 2 * MB4 * PAD; idx += 256)
    ((f16*)hbuf)[idx] = (f16)0.f;
  __syncthreads();

  float c_st = 0.f, hlast = 0.f;
  int jj = 16 * w + l;
  int tbase = 16 * w + l;  // gate column offset within a table row

  // x-pipeline prologue: wx for s=0 (regs), tok for s=1 (reg)
  float wxc[4];
  {
    int pos0 = dir ? (SS - 1) : 0;
    int base = (int)tok_s[pos0 * MB4 + q] * TSTR + tbase;
    wxc[0] = table[base];       wxc[1] = table[base + 64];
    wxc[2] = table[base + 128]; wxc[3] = table[base + 192];
  }
  int tok1;
  {
    int pos1 = dir ? (SS - 2) : 1;
    tok1 = (int)tok_s[pos1 * MB4 + q];
  }

#pragma unroll 2
  for (int s = 0; s < SS; ++s) {
    int p = s & 1;
    // critical path: h fragments (A[m=l][k=q*8+j] = h[bsel][k], 4x dup rows)
    f16x8 a0 = *(const f16x8*)&hbuf[p][bsel][q * 8];
    f16x8 a1 = *(const f16x8*)&hbuf[p][bsel][32 + q * 8];
    // off-path: wx prefetch for s+1 (tok1 from pipeline), tok fetch for s+2
    float wxn[4];
    {
      int base = tok1 * TSTR + tbase;
      wxn[0] = table[base];       wxn[1] = table[base + 64];
      wxn[2] = table[base + 128]; wxn[3] = table[base + 192];
    }
    {
      int pos2 = (dir ? (SS - 3 - s) : (s + 2)) & (SS - 1);  // wrapped values unused
      tok1 = (int)tok_s[pos2 * MB4 + q];
    }

    // r9-verified serial C-chain: C-init = x-projection, 2-deep MFMA per gate type
    f32x4 acc[4];
#pragma unroll
    for (int tt = 0; tt < 4; ++tt) {
      f32x4 ci = {wxc[tt], wxc[tt], wxc[tt], wxc[tt]};
      acc[tt] = __builtin_amdgcn_mfma_f32_16x16x32_f16(a0, Bf[tt][0], ci, 0, 0, 0);
    }
#pragma unroll
    for (int tt = 0; tt < 4; ++tt)
      acc[tt] = __builtin_amdgcn_mfma_f32_16x16x32_f16(a1, Bf[tt][1], acc[tt], 0, 0, 0);

    // activation (verified r6-r11): Ei=e^-i, Ef=e^-f, Eo=e^-o, G=e^2g
    {
      float Ei = fexp2(acc[0][0]);
      float Ef = fexp2(acc[1][0]);
      float G  = fexp2(acc[2][0]);
      float Eo = fexp2(acc[3][0]);
      float Ei1 = Ei + 1.f, Ef1 = Ef + 1.f, G1 = G + 1.f, Gm = G - 1.f;
      float t1 = Ei1 * G1;
      float num = fmaf(c_st, t1, Gm * Ef1);
      float cv = num * frcp(t1 * Ef1);
      c_st = cv;
      float C = fexp2((2.f * LOG2E) * cv);
      float hv = (C - 1.f) * frcp((Eo + 1.f) * (C + 1.f));
      hlast = hv;
      hbuf[p ^ 1][q][jj] = (f16)hv;
    }
    __syncthreads();
    wxc[0] = wxn[0]; wxc[1] = wxn[1]; wxc[2] = wxn[2]; wxc[3] = wxn[3];
  }

  // epilogue (separate codegen region)
  hs[q][jj] = hlast;
  epilogue_fn(t, dir, b0, mode, lens_packed,
              &hs[0][0], tok_s, (float*)red, w1s, avg2, c1w2, &c2r[0][0],
              conv1_w, conv2_w, conv2_b, fc1_w, fc1_b, fc1acc);
}

// ---- fc2 + softmax over accumulated fc1: 2 blocks x 256 threads, 1 batch/thread ----
__global__ void fin_kernel(const float* fc1acc, const void* fc2_w, const void* fc2_b,
                           const void* bvec, void* out) {
  int t = threadIdx.x;
  __shared__ int mode_sh;
  __shared__ float f2w[128];
  if (t == 0) mode_sh = 1;
  __syncthreads();
  {
    float v = bf2f(((const u16*)bvec)[t]);
    if (!(fabsf(v) < 1000.0f)) atomicAnd(&mode_sh, 0);
  }
  __syncthreads();
  int mode = mode_sh;
  if (t < 128) f2w[t] = ldw(fc2_w, t, mode);
  __syncthreads();

  int b = blockIdx.x * 256 + t;
  const float* f = fc1acc + (size_t)b * 64;
  float x0 = ldw(fc2_b, 0, mode), x1 = ldw(fc2_b, 1, mode);
#pragma unroll
  for (int m = 0; m < 64; ++m) {
    float fv = f[m];
    x0 = fmaf(fv, f2w[m], x0);
    x1 = fmaf(fv, f2w[64 + m], x1);
  }
  float mx = fmaxf(x0, x1);
  float e0 = fexp2(LOG2E * (x0 - mx)), e1 = fexp2(LOG2E * (x1 - mx));
  float inv = frcp(e0 + e1);
  if (mode) {
    ((__hip_bfloat16*)out)[b * 2 + 0] = __float2bfloat16(e0 * inv);
    ((__hip_bfloat16*)out)[b * 2 + 1] = __float2bfloat16(e1 * inv);
  } else {
    ((float*)out)[b * 2 + 0] = e0 * inv;
    ((float*)out)[b * 2 + 1] = e1 * inv;
  }
}

extern "C" void kernel_launch(void* const* d_in, const int* in_sizes, int n_in,
                              void* d_out, int out_size, void* d_ws, size_t ws_size,
                              hipStream_t stream) {
  (void)in_sizes; (void)n_in; (void)out_size; (void)ws_size;
  float* fc1acc = (float*)d_ws;  // 512*64 floats = 128 KB

  hipMemsetAsync(fc1acc, 0, (size_t)BB * 64 * sizeof(float), stream);
  lstm_kernel<<<256, 256, 0, stream>>>(d_in[0],
                                       d_in[1], d_in[2], d_in[3],
                                       d_in[4], d_in[5], d_in[6],
                                       d_in[7], d_in[8], d_in[9],
                                       d_in[10], d_in[11],
                                       fc1acc);
  fin_kernel<<<2, 256, 0, stream>>>(fc1acc, d_in[12], d_in[13], d_in[3], d_out);
}

// Round 13
// 422.529 us; speedup vs baseline: 1.1075x; 1.1075x over previous
//
#include <hip/hip_runtime.h>
#include <hip/hip_bf16.h>

#define BB 512
#define SS 1024
#define NI 20
#define HH 64
#define NG 256   // 4*H
#define MB4 4    // batch-dirs per block (1 cell per lane)
#define PAD 80   // h-row stride in f16
#define TSTR 257 // x-table row stride (floats)

typedef unsigned short u16;
typedef unsigned int u32;
typedef unsigned long long u64;
typedef _Float16 f16;
typedef f16 f16x8 __attribute__((ext_vector_type(8)));
typedef float f32x4 __attribute__((ext_vector_type(4)));

#define LOG2E 1.4426950408889634f

__device__ __forceinline__ float bf2f(u16 b) { return __uint_as_float(((u32)b) << 16); }
// mode==1: data is bf16; mode==0: data is fp32
__device__ __forceinline__ float ldw(const void* p, int idx, int mode) {
  return mode ? bf2f(((const u16*)p)[idx]) : ((const float*)p)[idx];
}
__device__ __forceinline__ float frcp(float x) { return __builtin_amdgcn_rcpf(x); }
__device__ __forceinline__ float fexp2(float x) { return __builtin_amdgcn_exp2f(x); }

// ---- BiLSTM (r9-verified, byte-identical loop; NO epilogue -- r11/r12 lesson:
// any fused epilogue inflates whole-function VGPR (52->104/140, spills) and
// degrades the K-loop's software pipelining by ~70-95 us). 256 blocks x 256 thr,
// 1 wave/SIMD. Block = (dir, 4 batches). Wave w owns units 16w..16w+15, 4 gate
// types in-lane; lane (l,q) = cell (batch q, unit 16w+l); A-rows dup h[l>>2] 4x.
// x-projection rides MFMA C-init from LDS table (prefetched 1 step ahead) ->
// 8 MFMA/step in ONE serial C-chain per gate type (r10: C-forwarding is free).
// Weights prescaled: i,f,o rows by -log2e, g rows by +2log2e (exp2-ready gates).
__global__ __launch_bounds__(256)
void lstm_kernel(const void* in1,
                 const void* Wih_f, const void* Whh_f, const void* b_f,
                 const void* Wih_b, const void* Whh_b, const void* b_b,
                 short* toks_g, int* lens, float* hout) {
  int bx = blockIdx.x;          // 0..255
  int dir = bx >> 7;
  int b0 = (bx & 127) * MB4;
  int t = threadIdx.x;
  int w = t >> 6, lane = t & 63, l = lane & 15, q = lane >> 4;
  int bsel = l >> 2;            // batch whose h this lane's A-row carries

  __shared__ __align__(16) float table[21 * TSTR];  // 21.6 KB; doubles as extract staging
  __shared__ __align__(16) f16 hbuf[2][MB4][PAD];
  __shared__ short tok_s[SS * MB4];                 // [pos][m], stores tok+1
  __shared__ u64 red[256];
  __shared__ int mode_sh;

  // ---- mode probe: b_f read as bf16; fp32 shows wild exponents ----
  if (t == 0) mode_sh = 1;
  __syncthreads();
  {
    float v = bf2f(((const u16*)b_f)[t]);
    if (!(fabsf(v) < 1000.0f)) atomicAnd(&mode_sh, 0);
  }
  __syncthreads();
  int mode = mode_sh;
  const void* Wih = dir ? Wih_b : Wih_f;
  const void* Whh = dir ? Whh_b : Whh_f;
  const void* bv  = dir ? b_b   : b_f;

  // ---- token extraction for this block's 4 batches (staged through `table` memory) ----
  u64 cnt = 0;  // packed 4x16-bit valid counts
  for (int m = 0; m < MB4; ++m) {
    if (mode) {
      u32* st = (u32*)table;
      for (int k0 = 0; k0 < 4; ++k0) {
        const u32* src = (const u32*)in1 + ((size_t)(b0 + m) * SS + k0 * 256) * 10;
#pragma unroll
        for (int i = 0; i < 10; ++i) st[t + i * 256] = src[t + i * 256];  // coalesced
        __syncthreads();
        const u32* row = st + t * 10;
        int tok = -1;
#pragma unroll
        for (int ww = 0; ww < 10; ++ww) {
          u32 u = row[ww];
          if (u & 0xFFFFu) tok = 2 * ww;
          if (u >> 16)     tok = 2 * ww + 1;
        }
        tok_s[(k0 * 256 + t) * MB4 + m] = (short)(tok + 1);
        if (dir == 0) toks_g[(size_t)(b0 + m) * SS + k0 * 256 + t] = (short)tok;
        cnt += (u64)(tok >= 0) << (16 * m);
        __syncthreads();
      }
    } else {
      float4* st = (float4*)table;
      for (int k0 = 0; k0 < 4; ++k0) {
        const float4* src = (const float4*)((const float*)in1 + ((size_t)(b0 + m) * SS + k0 * 256) * 20);
#pragma unroll
        for (int i = 0; i < 5; ++i) st[t + i * 256] = src[t + i * 256];  // coalesced 16B/lane
        __syncthreads();
        const float* row = (const float*)table + t * 20;
        int tok = -1;
#pragma unroll
        for (int ww = 0; ww < 20; ++ww)
          if (row[ww] != 0.f) tok = ww;
        tok_s[(k0 * 256 + t) * MB4 + m] = (short)(tok + 1);
        if (dir == 0) toks_g[(size_t)(b0 + m) * SS + k0 * 256 + t] = (short)tok;
        cnt += (u64)(tok >= 0) << (16 * m);
        __syncthreads();
      }
    }
  }
  // lens: packed u64 tree reduction (fwd blocks export)
  red[t] = cnt;
  __syncthreads();
  for (int stp = 128; stp > 0; stp >>= 1) {
    if (t < stp) red[t] += red[t + stp];
    __syncthreads();
  }
  if (dir == 0 && t < MB4)
    lens[b0 + t] = (int)((red[0] >> (16 * t)) & 0xFFFFull);
  __syncthreads();

  // ---- x-projection table: table[tok+1][g] = scl_g * (W_ih[g][tok] + b[g]); row 0 = bias ----
  for (int idx = t; idx < 21 * 256; idx += 256) {
    int r = idx >> 8, g = idx & 255;
    float scl = ((g >> 6) == 2) ? (2.f * LOG2E) : (-LOG2E);
    float v = ldw(bv, g, mode);
    if (r > 0) v += ldw(Wih, g * NI + (r - 1), mode);
    table[r * TSTR + g] = scl * v;
  }
  // ---- W_hh B-fragments: n=lane&15 -> gate col (unit 16w+l, type tt), k=q*8+j ----
  f16x8 Bf[4][2];
#pragma unroll
  for (int tt = 0; tt < 4; ++tt) {
    float scl = (tt == 2) ? (2.f * LOG2E) : (-LOG2E);
    int g = 64 * tt + 16 * w + l;
#pragma unroll
    for (int kc = 0; kc < 2; ++kc) {
      f16x8 v;
#pragma unroll
      for (int j = 0; j < 8; ++j)
        v[j] = (f16)(scl * ldw(Whh, g * HH + kc * 32 + q * 8 + j, mode));
      Bf[tt][kc] = v;
    }
  }
  for (int idx = t; idx < 2 * MB4 * PAD; idx += 256)
    ((f16*)hbuf)[idx] = (f16)0.f;
  __syncthreads();

  float c_st = 0.f, hlast = 0.f;
  int jj = 16 * w + l;
  int tbase = 16 * w + l;  // gate column offset within a table row

  // x-pipeline prologue: wx for s=0 (regs), tok for s=1 (reg)
  float wxc[4];
  {
    int pos0 = dir ? (SS - 1) : 0;
    int base = (int)tok_s[pos0 * MB4 + q] * TSTR + tbase;
    wxc[0] = table[base];       wxc[1] = table[base + 64];
    wxc[2] = table[base + 128]; wxc[3] = table[base + 192];
  }
  int tok1;
  {
    int pos1 = dir ? (SS - 2) : 1;
    tok1 = (int)tok_s[pos1 * MB4 + q];
  }

#pragma unroll 2
  for (int s = 0; s < SS; ++s) {
    int p = s & 1;
    // critical path: h fragments (A[m=l][k=q*8+j] = h[bsel][k], 4x dup rows)
    f16x8 a0 = *(const f16x8*)&hbuf[p][bsel][q * 8];
    f16x8 a1 = *(const f16x8*)&hbuf[p][bsel][32 + q * 8];
    // off-path: wx prefetch for s+1 (tok1 from pipeline), tok fetch for s+2
    float wxn[4];
    {
      int base = tok1 * TSTR + tbase;
      wxn[0] = table[base];       wxn[1] = table[base + 64];
      wxn[2] = table[base + 128]; wxn[3] = table[base + 192];
    }
    {
      int pos2 = (dir ? (SS - 3 - s) : (s + 2)) & (SS - 1);  // wrapped values unused
      tok1 = (int)tok_s[pos2 * MB4 + q];
    }

    // r9-verified serial C-chain: C-init = x-projection, 2-deep MFMA per gate type
    f32x4 acc[4];
#pragma unroll
    for (int tt = 0; tt < 4; ++tt) {
      f32x4 ci = {wxc[tt], wxc[tt], wxc[tt], wxc[tt]};
      acc[tt] = __builtin_amdgcn_mfma_f32_16x16x32_f16(a0, Bf[tt][0], ci, 0, 0, 0);
    }
#pragma unroll
    for (int tt = 0; tt < 4; ++tt)
      acc[tt] = __builtin_amdgcn_mfma_f32_16x16x32_f16(a1, Bf[tt][1], acc[tt], 0, 0, 0);

    // activation (verified r6-r12): Ei=e^-i, Ef=e^-f, Eo=e^-o, G=e^2g
    {
      float Ei = fexp2(acc[0][0]);
      float Ef = fexp2(acc[1][0]);
      float G  = fexp2(acc[2][0]);
      float Eo = fexp2(acc[3][0]);
      float Ei1 = Ei + 1.f, Ef1 = Ef + 1.f, G1 = G + 1.f, Gm = G - 1.f;
      float t1 = Ei1 * G1;
      float num = fmaf(c_st, t1, Gm * Ef1);
      float cv = num * frcp(t1 * Ef1);
      c_st = cv;
      float C = fexp2((2.f * LOG2E) * cv);
      float hv = (C - 1.f) * frcp((Eo + 1.f) * (C + 1.f));
      hlast = hv;
      hbuf[p ^ 1][q][jj] = (f16)hv;
    }
    __syncthreads();
    wxc[0] = wxn[0]; wxc[1] = wxn[1]; wxc[2] = wxn[2]; wxc[3] = wxn[3];
  }
  hout[(b0 + q) * 128 + dir * 64 + jj] = hlast;
}

// ---- light head: 512 blocks x 128 threads, 1 batch/block, NO heavy LDS staging.
// conv2_w/fc1_w/fc2_w read straight from global (L2-hot after the first blocks;
// r9 lesson: 90 KB/block LDS staging cost ~50 us via occupancy + 23 MB refetch).
__global__ __launch_bounds__(128)
void head_kernel(const void* conv1_w, const void* conv2_w, const void* conv2_b,
                 const void* fc1_w, const void* fc1_b,
                 const void* fc2_w, const void* fc2_b,
                 const void* bvec, const short* toks, const int* lens,
                 const float* hout, void* out) {
  int b = blockIdx.x;
  int t = threadIdx.x;  // 128 threads
  __shared__ float c1w[400];
  __shared__ short tok_s[SS];
  __shared__ float avg[80];
  __shared__ float merged[228];
  __shared__ float fc1v[64];
  __shared__ int mode_sh;

  if (t == 0) mode_sh = 1;
  __syncthreads();
  {
    float v0 = bf2f(((const u16*)bvec)[t]);
    float v1 = bf2f(((const u16*)bvec)[128 + t]);
    if (!(fabsf(v0) < 1000.0f) || !(fabsf(v1) < 1000.0f)) atomicAnd(&mode_sh, 0);
  }
  __syncthreads();
  int mode = mode_sh;

  for (int i = t; i < 400; i += 128) c1w[i] = ldw(conv1_w, i, mode);
  for (int s = t; s < SS; s += 128) tok_s[s] = toks[(size_t)b * SS + s];
  __syncthreads();

  int len = lens[b];
  int bw = len >> 2;
  if (t < 80) {
    int k = t / 20, cc = t % 20;
    float sum = 0.f;
    for (int s = k * bw; s < (k + 1) * bw; ++s) {
      // faithful torch reshape: c1r[b,s,cc] lives at flat f = s*20+cc of the [20,1024] map
      int f = s * 20 + cc;
      int tk = tok_s[f & 1023];
      if (tk >= 0) sum += c1w[(f >> 10) * 20 + tk];  // padding rows contribute 0
    }
    avg[t] = sum / (float)bw;
  }
  __syncthreads();

  if (t < 100) {
    float dot = ldw(conv2_b, t, mode);
#pragma unroll 4
    for (int q = 0; q < 80; ++q)
      dot += avg[q] * ldw(conv2_w, t * 80 + q, mode);
    merged[128 + t] = dot > 0.f ? dot : 0.f;  // relu
  }
  merged[t] = hout[b * 128 + t];  // [h_fw | h_bw]
  __syncthreads();

  if (t < 64) {
    float v = ldw(fc1_b, t, mode);
#pragma unroll 4
    for (int m = 0; m < 228; ++m)
      v += merged[m] * ldw(fc1_w, t * 228 + m, mode);
    fc1v[t] = v;   // no activation on fc1 per reference
  }
  __syncthreads();

  if (t == 0) {
    float x0 = ldw(fc2_b, 0, mode), x1 = ldw(fc2_b, 1, mode);
#pragma unroll 4
    for (int m = 0; m < 64; ++m) {
      x0 = fmaf(fc1v[m], ldw(fc2_w, m, mode), x0);
      x1 = fmaf(fc1v[m], ldw(fc2_w, 64 + m, mode), x1);
    }
    float mx = fmaxf(x0, x1);
    float e0 = fexp2(LOG2E * (x0 - mx)), e1 = fexp2(LOG2E * (x1 - mx));
    float inv = frcp(e0 + e1);
    if (mode) {
      ((__hip_bfloat16*)out)[b * 2 + 0] = __float2bfloat16(e0 * inv);
      ((__hip_bfloat16*)out)[b * 2 + 1] = __float2bfloat16(e1 * inv);
    } else {
      ((float*)out)[b * 2 + 0] = e0 * inv;
      ((float*)out)[b * 2 + 1] = e1 * inv;
    }
  }
}

extern "C" void kernel_launch(void* const* d_in, const int* in_sizes, int n_in,
                              void* d_out, int out_size, void* d_ws, size_t ws_size,
                              hipStream_t stream) {
  (void)in_sizes; (void)n_in; (void)out_size; (void)ws_size;
  char* ws = (char*)d_ws;
  int*   lens = (int*)(ws + 256);                             // 2 KB
  short* toks = (short*)(ws + 256 + 2048);                    // 1 MB
  float* hout = (float*)(ws + 256 + 2048 + (size_t)BB * SS * sizeof(short)); // 256 KB

  lstm_kernel<<<256, 256, 0, stream>>>(d_in[0],
                                       d_in[1], d_in[2], d_in[3],
                                       d_in[4], d_in[5], d_in[6],
                                       toks, lens, hout);
  head_kernel<<<BB, 128, 0, stream>>>(d_in[7], d_in[8], d_in[9],
                                      d_in[10], d_in[11], d_in[12], d_in[13],
                                      d_in[3], toks, lens, hout, d_out);
}

// Round 14
// 390.098 us; speedup vs baseline: 1.1996x; 1.0831x over previous
//
#include <hip/hip_runtime.h>
#include <hip/hip_bf16.h>

#define BB 512
#define SS 1024
#define NI 20
#define HH 64
#define NG 256   // 4*H
#define MB4 4    // batch-dirs per block (1 cell per lane)
#define PAD 80   // h-row stride in f16
#define TSTR 257 // x-table row stride (floats)

typedef unsigned short u16;
typedef unsigned int u32;
typedef unsigned long long u64;
typedef _Float16 f16;
typedef f16 f16x8 __attribute__((ext_vector_type(8)));
typedef float f32x4 __attribute__((ext_vector_type(4)));

#define LOG2E 1.4426950408889634f

__device__ __forceinline__ float bf2f(u16 b) { return __uint_as_float(((u32)b) << 16); }
// mode==1: data is bf16; mode==0: data is fp32
__device__ __forceinline__ float ldw(const void* p, int idx, int mode) {
  return mode ? bf2f(((const u16*)p)[idx]) : ((const float*)p)[idx];
}
__device__ __forceinline__ float frcp(float x) { return __builtin_amdgcn_rcpf(x); }
__device__ __forceinline__ float fexp2(float x) { return __builtin_amdgcn_exp2f(x); }

// ---- BiLSTM (r9-verified, byte-identical loop; NO epilogue -- r11/r12 lesson:
// any fused epilogue inflates whole-function VGPR (52->104/140, spills) and
// degrades the K-loop's software pipelining by ~70-95 us). 256 blocks x 256 thr,
// 1 wave/SIMD. Block = (dir, 4 batches). Wave w owns units 16w..16w+15, 4 gate
// types in-lane; lane (l,q) = cell (batch q, unit 16w+l); A-rows dup h[l>>2] 4x.
// x-projection rides MFMA C-init from LDS table (prefetched 1 step ahead) ->
// 8 MFMA/step in ONE serial C-chain per gate type (r10: C-forwarding is free).
// Weights prescaled: i,f,o rows by -log2e, g rows by +2log2e (exp2-ready gates).
__global__ __launch_bounds__(256)
void lstm_kernel(const void* in1,
                 const void* Wih_f, const void* Whh_f, const void* b_f,
                 const void* Wih_b, const void* Whh_b, const void* b_b,
                 short* toks_g, int* lens, float* hout) {
  int bx = blockIdx.x;          // 0..255
  int dir = bx >> 7;
  int b0 = (bx & 127) * MB4;
  int t = threadIdx.x;
  int w = t >> 6, lane = t & 63, l = lane & 15, q = lane >> 4;
  int bsel = l >> 2;            // batch whose h this lane's A-row carries

  __shared__ __align__(16) float table[21 * TSTR];  // 21.6 KB; doubles as extract staging
  __shared__ __align__(16) f16 hbuf[2][MB4][PAD];
  __shared__ short tok_s[SS * MB4];                 // [pos][m], stores tok+1
  __shared__ u64 red[256];
  __shared__ int mode_sh;

  // ---- mode probe: b_f read as bf16; fp32 shows wild exponents ----
  if (t == 0) mode_sh = 1;
  __syncthreads();
  {
    float v = bf2f(((const u16*)b_f)[t]);
    if (!(fabsf(v) < 1000.0f)) atomicAnd(&mode_sh, 0);
  }
  __syncthreads();
  int mode = mode_sh;
  const void* Wih = dir ? Wih_b : Wih_f;
  const void* Whh = dir ? Whh_b : Whh_f;
  const void* bv  = dir ? b_b   : b_f;

  // ---- token extraction for this block's 4 batches (staged through `table` memory) ----
  u64 cnt = 0;  // packed 4x16-bit valid counts
  for (int m = 0; m < MB4; ++m) {
    if (mode) {
      u32* st = (u32*)table;
      for (int k0 = 0; k0 < 4; ++k0) {
        const u32* src = (const u32*)in1 + ((size_t)(b0 + m) * SS + k0 * 256) * 10;
#pragma unroll
        for (int i = 0; i < 10; ++i) st[t + i * 256] = src[t + i * 256];  // coalesced
        __syncthreads();
        const u32* row = st + t * 10;
        int tok = -1;
#pragma unroll
        for (int ww = 0; ww < 10; ++ww) {
          u32 u = row[ww];
          if (u & 0xFFFFu) tok = 2 * ww;
          if (u >> 16)     tok = 2 * ww + 1;
        }
        tok_s[(k0 * 256 + t) * MB4 + m] = (short)(tok + 1);
        if (dir == 0) toks_g[(size_t)(b0 + m) * SS + k0 * 256 + t] = (short)tok;
        cnt += (u64)(tok >= 0) << (16 * m);
        __syncthreads();
      }
    } else {
      float4* st = (float4*)table;
      for (int k0 = 0; k0 < 4; ++k0) {
        const float4* src = (const float4*)((const float*)in1 + ((size_t)(b0 + m) * SS + k0 * 256) * 20);
#pragma unroll
        for (int i = 0; i < 5; ++i) st[t + i * 256] = src[t + i * 256];  // coalesced 16B/lane
        __syncthreads();
        const float* row = (const float*)table + t * 20;
        int tok = -1;
#pragma unroll
        for (int ww = 0; ww < 20; ++ww)
          if (row[ww] != 0.f) tok = ww;
        tok_s[(k0 * 256 + t) * MB4 + m] = (short)(tok + 1);
        if (dir == 0) toks_g[(size_t)(b0 + m) * SS + k0 * 256 + t] = (short)tok;
        cnt += (u64)(tok >= 0) << (16 * m);
        __syncthreads();
      }
    }
  }
  // lens: packed u64 tree reduction (fwd blocks export)
  red[t] = cnt;
  __syncthreads();
  for (int stp = 128; stp > 0; stp >>= 1) {
    if (t < stp) red[t] += red[t + stp];
    __syncthreads();
  }
  if (dir == 0 && t < MB4)
    lens[b0 + t] = (int)((red[0] >> (16 * t)) & 0xFFFFull);
  __syncthreads();

  // ---- x-projection table: table[tok+1][g] = scl_g * (W_ih[g][tok] + b[g]); row 0 = bias ----
  for (int idx = t; idx < 21 * 256; idx += 256) {
    int r = idx >> 8, g = idx & 255;
    float scl = ((g >> 6) == 2) ? (2.f * LOG2E) : (-LOG2E);
    float v = ldw(bv, g, mode);
    if (r > 0) v += ldw(Wih, g * NI + (r - 1), mode);
    table[r * TSTR + g] = scl * v;
  }
  // ---- W_hh B-fragments: n=lane&15 -> gate col (unit 16w+l, type tt), k=q*8+j ----
  f16x8 Bf[4][2];
#pragma unroll
  for (int tt = 0; tt < 4; ++tt) {
    float scl = (tt == 2) ? (2.f * LOG2E) : (-LOG2E);
    int g = 64 * tt + 16 * w + l;
#pragma unroll
    for (int kc = 0; kc < 2; ++kc) {
      f16x8 v;
#pragma unroll
      for (int j = 0; j < 8; ++j)
        v[j] = (f16)(scl * ldw(Whh, g * HH + kc * 32 + q * 8 + j, mode));
      Bf[tt][kc] = v;
    }
  }
  for (int idx = t; idx < 2 * MB4 * PAD; idx += 256)
    ((f16*)hbuf)[idx] = (f16)0.f;
  __syncthreads();

  float c_st = 0.f, hlast = 0.f;
  int jj = 16 * w + l;
  int tbase = 16 * w + l;  // gate column offset within a table row

  // x-pipeline prologue: wx for s=0 (regs), tok for s=1 (reg)
  float wxc[4];
  {
    int pos0 = dir ? (SS - 1) : 0;
    int base = (int)tok_s[pos0 * MB4 + q] * TSTR + tbase;
    wxc[0] = table[base];       wxc[1] = table[base + 64];
    wxc[2] = table[base + 128]; wxc[3] = table[base + 192];
  }
  int tok1;
  {
    int pos1 = dir ? (SS - 2) : 1;
    tok1 = (int)tok_s[pos1 * MB4 + q];
  }

#pragma unroll 2
  for (int s = 0; s < SS; ++s) {
    int p = s & 1;
    // critical path: h fragments (A[m=l][k=q*8+j] = h[bsel][k], 4x dup rows)
    f16x8 a0 = *(const f16x8*)&hbuf[p][bsel][q * 8];
    f16x8 a1 = *(const f16x8*)&hbuf[p][bsel][32 + q * 8];
    // off-path: wx prefetch for s+1 (tok1 from pipeline), tok fetch for s+2
    float wxn[4];
    {
      int base = tok1 * TSTR + tbase;
      wxn[0] = table[base];       wxn[1] = table[base + 64];
      wxn[2] = table[base + 128]; wxn[3] = table[base + 192];
    }
    {
      int pos2 = (dir ? (SS - 3 - s) : (s + 2)) & (SS - 1);  // wrapped values unused
      tok1 = (int)tok_s[pos2 * MB4 + q];
    }

    // r9-verified serial C-chain: C-init = x-projection, 2-deep MFMA per gate type
    f32x4 acc[4];
#pragma unroll
    for (int tt = 0; tt < 4; ++tt) {
      f32x4 ci = {wxc[tt], wxc[tt], wxc[tt], wxc[tt]};
      acc[tt] = __builtin_amdgcn_mfma_f32_16x16x32_f16(a0, Bf[tt][0], ci, 0, 0, 0);
    }
#pragma unroll
    for (int tt = 0; tt < 4; ++tt)
      acc[tt] = __builtin_amdgcn_mfma_f32_16x16x32_f16(a1, Bf[tt][1], acc[tt], 0, 0, 0);

    // activation (verified r6-r13): Ei=e^-i, Ef=e^-f, Eo=e^-o, G=e^2g
    {
      float Ei = fexp2(acc[0][0]);
      float Ef = fexp2(acc[1][0]);
      float G  = fexp2(acc[2][0]);
      float Eo = fexp2(acc[3][0]);
      float Ei1 = Ei + 1.f, Ef1 = Ef + 1.f, G1 = G + 1.f, Gm = G - 1.f;
      float t1 = Ei1 * G1;
      float num = fmaf(c_st, t1, Gm * Ef1);
      float cv = num * frcp(t1 * Ef1);
      c_st = cv;
      float C = fexp2((2.f * LOG2E) * cv);
      float hv = (C - 1.f) * frcp((Eo + 1.f) * (C + 1.f));
      hlast = hv;
      hbuf[p ^ 1][q][jj] = (f16)hv;
    }
    __syncthreads();
    wxc[0] = wxn[0]; wxc[1] = wxn[1]; wxc[2] = wxn[2]; wxc[3] = wxn[3];
  }
  hout[(b0 + q) * 128 + dir * 64 + jj] = hlast;
}

// ---- head, latency-optimized: 512 blocks x 256 thr (8 waves/CU), every phase
// split across max threads with manual unrolling for independent load chains.
// (r13 lesson: the head was ~50 us of latency-bound serial loops -- dependent
// LDS chain in the ragged mean (2x ~120cyc per iter) + scattered L2 dots on
// <=100 threads with 2 waves/block. Bandwidth was never the issue.)
__global__ __launch_bounds__(256)
void head_kernel(const void* conv1_w, const void* conv2_w, const void* conv2_b,
                 const void* fc1_w, const void* fc1_b,
                 const void* fc2_w, const void* fc2_b,
                 const void* bvec, const short* toks, const int* lens,
                 const float* hout, void* out) {
  int b = blockIdx.x;
  int t = threadIdx.x;  // 256 threads
  __shared__ float c1w[400];
  __shared__ short tok_s[SS];
  __shared__ float pav[3][80];
  __shared__ float avg[80];
  __shared__ float cpart[2][100];
  __shared__ float merged[228];
  __shared__ float fpart[4][64];
  __shared__ float fc1v[64];
  __shared__ float f2p[2][64];
  __shared__ int mode_sh;

  if (t == 0) mode_sh = 1;
  __syncthreads();
  {
    float v = bf2f(((const u16*)bvec)[t]);
    if (!(fabsf(v) < 1000.0f)) atomicAnd(&mode_sh, 0);
  }
  __syncthreads();
  int mode = mode_sh;

  for (int i = t; i < 400; i += 256) c1w[i] = ldw(conv1_w, i, mode);
  for (int s = t; s < SS; s += 256) tok_s[s] = toks[(size_t)b * SS + s];
  __syncthreads();

  int len = lens[b];
  int bw = len >> 2;
  // ragged 4-bin mean: 240 threads = 80 (k,cc) units x 3 segments; 4 independent
  // partial-sum chains per thread so the tok->c1w dependent LDS reads pipeline.
  if (t < 240) {
    int seg = t / 80;
    int u = t - seg * 80;
    int k = u / 20, cc = u % 20;
    int base = k * bw;
    int s0 = base + (seg * bw) / 3;
    int s1 = base + ((seg + 1) * bw) / 3;
    float p0 = 0.f, p1 = 0.f, p2 = 0.f, p3 = 0.f;
    int s = s0;
    for (; s + 4 <= s1; s += 4) {
      // faithful torch reshape: flat f = s*20+cc of the [20,1024] map
      int f0 = s * 20 + cc, f1 = f0 + 20, f2 = f0 + 40, f3 = f0 + 60;
      int tk0 = tok_s[f0 & 1023];
      int tk1 = tok_s[f1 & 1023];
      int tk2 = tok_s[f2 & 1023];
      int tk3 = tok_s[f3 & 1023];
      if (tk0 >= 0) p0 += c1w[(f0 >> 10) * 20 + tk0];
      if (tk1 >= 0) p1 += c1w[(f1 >> 10) * 20 + tk1];
      if (tk2 >= 0) p2 += c1w[(f2 >> 10) * 20 + tk2];
      if (tk3 >= 0) p3 += c1w[(f3 >> 10) * 20 + tk3];
    }
    for (; s < s1; ++s) {
      int f = s * 20 + cc;
      int tk = tok_s[f & 1023];
      if (tk >= 0) p0 += c1w[(f >> 10) * 20 + tk];
    }
    pav[seg][u] = (p0 + p1) + (p2 + p3);
  }
  __syncthreads();
  if (t < 80) avg[t] = (pav[0][t] + pav[1][t] + pav[2][t]) / (float)bw;
  __syncthreads();

  // conv2: 200 threads = 100 outputs x 2 K-halves of 40, unroll 8
  if (t < 200) {
    int half = t / 100, o = t - half * 100;
    float dot = 0.f;
    int q0 = half * 40;
#pragma unroll 8
    for (int q = q0; q < q0 + 40; ++q)
      dot = fmaf(avg[q], ldw(conv2_w, o * 80 + q, mode), dot);
    cpart[half][o] = dot;
  }
  if (t < 128) merged[t] = hout[b * 128 + t];  // [h_fw | h_bw]
  __syncthreads();
  if (t < 100) {
    float dot = cpart[0][t] + cpart[1][t] + ldw(conv2_b, t, mode);
    merged[128 + t] = dot > 0.f ? dot : 0.f;  // relu
  }
  __syncthreads();

  // fc1: 256 threads = 64 outputs x 4 K-chunks of 57, unroll 8
  {
    int o = t & 63, ch = t >> 6;
    float v = 0.f;
    int m0 = ch * 57;
#pragma unroll 8
    for (int m = m0; m < m0 + 57; ++m)
      v = fmaf(merged[m], ldw(fc1_w, o * 228 + m, mode), v);
    fpart[ch][o] = v;
  }
  __syncthreads();
  if (t < 64)
    fc1v[t] = fpart[0][t] + fpart[1][t] + fpart[2][t] + fpart[3][t] + ldw(fc1_b, t, mode);
  __syncthreads();

  // fc2: 128 threads compute products, tree-reduce
  if (t < 128) {
    int o = t >> 6, m = t & 63;
    f2p[o][m] = fc1v[m] * ldw(fc2_w, o * 64 + m, mode);
  }
  __syncthreads();
  for (int stp = 32; stp > 0; stp >>= 1) {
    if (t < 128) {
      int o = t >> 6, m = t & 63;
      if (m < stp) f2p[o][m] += f2p[o][m + stp];
    }
    __syncthreads();
  }
  if (t == 0) {
    float x0 = f2p[0][0] + ldw(fc2_b, 0, mode);
    float x1 = f2p[1][0] + ldw(fc2_b, 1, mode);
    float mx = fmaxf(x0, x1);
    float e0 = fexp2(LOG2E * (x0 - mx)), e1 = fexp2(LOG2E * (x1 - mx));
    float inv = frcp(e0 + e1);
    if (mode) {
      ((__hip_bfloat16*)out)[b * 2 + 0] = __float2bfloat16(e0 * inv);
      ((__hip_bfloat16*)out)[b * 2 + 1] = __float2bfloat16(e1 * inv);
    } else {
      ((float*)out)[b * 2 + 0] = e0 * inv;
      ((float*)out)[b * 2 + 1] = e1 * inv;
    }
  }
}

extern "C" void kernel_launch(void* const* d_in, const int* in_sizes, int n_in,
                              void* d_out, int out_size, void* d_ws, size_t ws_size,
                              hipStream_t stream) {
  (void)in_sizes; (void)n_in; (void)out_size; (void)ws_size;
  char* ws = (char*)d_ws;
  int*   lens = (int*)(ws + 256);                             // 2 KB
  short* toks = (short*)(ws + 256 + 2048);                    // 1 MB
  float* hout = (float*)(ws + 256 + 2048 + (size_t)BB * SS * sizeof(short)); // 256 KB

  lstm_kernel<<<256, 256, 0, stream>>>(d_in[0],
                                       d_in[1], d_in[2], d_in[3],
                                       d_in[4], d_in[5], d_in[6],
                                       toks, lens, hout);
  head_kernel<<<BB, 256, 0, stream>>>(d_in[7], d_in[8], d_in[9],
                                      d_in[10], d_in[11], d_in[12], d_in[13],
                                      d_in[3], toks, lens, hout, d_out);
}